// Round 19
// baseline (280.143 us; speedup 1.0000x reference)
//
#include <hip/hip_runtime.h>

// CKConv: y[b,o,n] = sum_i (x[b,i] * k[o,i])_causal[n] + bias[o]
// Rank-33 kernel: kr[o,i,t] = sum_r hbT[r][t] * M2[r][i][o]
// FFT path: Yf[b,o,f] = sum_i Xf[b,i,f]*Kf[o,i,f],  Kf = sum_r Hf[r,f]*M2[r,i,o]
// K-build runs on MFMA (bf16 split-precision, 3 terms).

#define LSEQ   8192
#define N2     8192
#define HDIM   32
#define NB     33
#define NROWS  512
#define NFREQ  8193
#define FSTRIDE 8208     // complex row stride (16-aligned)
#define FBLK   8
#define FTH    1024
#define OMEGA0 30.0f
#define TWOPI  6.283185307179586f

#define IDX(i) ((i) + ((i) >> 4))
#define BR(k)  ((int)(__brev((unsigned)(k)) >> 19))

typedef __attribute__((ext_vector_type(8))) short bf16x8;
typedef __attribute__((ext_vector_type(4))) float f32x4;

__device__ __forceinline__ unsigned short f2bf(float v)
{
    unsigned u = __float_as_uint(v);
    return (unsigned short)((u + 0x7FFFu + ((u >> 16) & 1u)) >> 16);
}
__device__ __forceinline__ float bf2f(unsigned short h)
{
    return __uint_as_float(((unsigned)h) << 16);
}

// ---------------------------------------------------------------- twiddle table
__device__ __forceinline__ void build_table(float2* Tq, int tid)
{
    for (int t = tid; t <= 1024; t += FTH) {
        float s, c;
        __sincosf(TWOPI * (float)t / 8192.0f, &s, &c);
        Tq[t] = make_float2(c, s);
    }
}

// ---------------------------------------------------------------- 8192-pt C2C FFT core (radix-8 x4 + radix-2, bit-reversed out)
__device__ __forceinline__ void fft8192_core8(float* re, float* im,
                                              const float2* Tq, int tid)
{
    const float RC = 0.70710678118654752f;
    #pragma unroll
    for (int p = 10; p >= 1; p -= 3) {           // m = 1024,128,16,2
        int m = 1 << p;
        int tmul = 1 << (10 - p);
        __syncthreads();
        for (int u = tid; u < 1024; u += FTH) {
            int j = u & (m - 1);
            int base = ((u >> p) << (p + 3)) + j;
            float xr[8], xi[8];
            #pragma unroll
            for (int q = 0; q < 8; ++q) {
                int ix = IDX(base + q * m);
                xr[q] = re[ix]; xi[q] = im[ix];
            }
            float t0r=xr[0]+xr[4], t0i=xi[0]+xi[4];
            float t1r=xr[0]-xr[4], t1i=xi[0]-xi[4];
            float t2r=xr[2]+xr[6], t2i=xi[2]+xi[6];
            float t3r=xr[2]-xr[6], t3i=xi[2]-xi[6];
            float E0r=t0r+t2r, E0i=t0i+t2i;
            float E2r=t0r-t2r, E2i=t0i-t2i;
            float E1r=t1r+t3i, E1i=t1i-t3r;
            float E3r=t1r-t3i, E3i=t1i+t3r;
            float s0r=xr[1]+xr[5], s0i=xi[1]+xi[5];
            float s1r=xr[1]-xr[5], s1i=xi[1]-xi[5];
            float s2r=xr[3]+xr[7], s2i=xi[3]+xi[7];
            float s3r=xr[3]-xr[7], s3i=xi[3]-xi[7];
            float O0r=s0r+s2r, O0i=s0i+s2i;
            float O2r=s0r-s2r, O2i=s0i-s2i;
            float O1r=s1r+s3i, O1i=s1i-s3r;
            float O3r=s1r-s3i, O3i=s1i+s3r;
            float u1r=(O1r+O1i)*RC, u1i=(O1i-O1r)*RC;
            float u2r=O2i,          u2i=-O2r;
            float u3r=(O3i-O3r)*RC, u3i=-(O3r+O3i)*RC;
            float X0r=E0r+O0r, X0i=E0i+O0i;
            float X4r=E0r-O0r, X4i=E0i-O0i;
            float X1r=E1r+u1r, X1i=E1i+u1i;
            float X5r=E1r-u1r, X5i=E1i-u1i;
            float X2r=E2r+u2r, X2i=E2i+u2i;
            float X6r=E2r-u2r, X6i=E2i-u2i;
            float X3r=E3r+u3r, X3i=E3i+u3i;
            float X7r=E3r-u3r, X7i=E3i-u3i;
            float2 tq = Tq[j * tmul];
            float w1r = tq.x,               w1i = -tq.y;
            float w2r = w1r*w1r - w1i*w1i,  w2i = 2.f*w1r*w1i;
            float w3r = w2r*w1r - w2i*w1i,  w3i = w2r*w1i + w2i*w1r;
            float w4r = w2r*w2r - w2i*w2i,  w4i = 2.f*w2r*w2i;
            float w5r = w4r*w1r - w4i*w1i,  w5i = w4r*w1i + w4i*w1r;
            float w6r = w3r*w3r - w3i*w3i,  w6i = 2.f*w3r*w3i;
            float w7r = w4r*w3r - w4i*w3i,  w7i = w4r*w3i + w4i*w3r;
            int i0=IDX(base),       i1=IDX(base+m),   i2=IDX(base+2*m), i3=IDX(base+3*m);
            int i4=IDX(base+4*m),   i5=IDX(base+5*m), i6=IDX(base+6*m), i7=IDX(base+7*m);
            re[i0]=X0r;                     im[i0]=X0i;
            re[i1]=X4r*w4r - X4i*w4i;       im[i1]=X4r*w4i + X4i*w4r;
            re[i2]=X2r*w2r - X2i*w2i;       im[i2]=X2r*w2i + X2i*w2r;
            re[i3]=X6r*w6r - X6i*w6i;       im[i3]=X6r*w6i + X6i*w6r;
            re[i4]=X1r*w1r - X1i*w1i;       im[i4]=X1r*w1i + X1i*w1r;
            re[i5]=X5r*w5r - X5i*w5i;       im[i5]=X5r*w5i + X5i*w5r;
            re[i6]=X3r*w3r - X3i*w3i;       im[i6]=X3r*w3i + X3i*w3r;
            re[i7]=X7r*w7r - X7i*w7i;       im[i7]=X7r*w7i + X7i*w7r;
        }
    }
    __syncthreads();
    for (int u = tid; u < 4096; u += FTH) {
        int a = IDX(2 * u), b = IDX(2 * u + 1);
        float ar = re[a], ai = im[a];
        float br = re[b], bi = im[b];
        re[a] = ar + br; im[a] = ai + bi;
        re[b] = ar - br; im[b] = ai - bi;
    }
    __syncthreads();
}

// ---------------------------------------------------------------- merged forward kernel
// blocks 0..32: basis rows; 33..544: x rows; 545..800: M2 hi/lo bf16 prep
__global__ __launch_bounds__(FTH) void fwd_kernel(
    const float* __restrict__ x,
    const float* __restrict__ w1, const float* __restrict__ b1,
    const float* __restrict__ w2, const float* __restrict__ b2,
    const float* __restrict__ w3, const float* __restrict__ b3,
    float* __restrict__ Hf, float* __restrict__ XYf,
    unsigned short* __restrict__ M2hi, unsigned short* __restrict__ M2lo)
{
    int blk = blockIdx.x;
    int tid = threadIdx.x;

    if (blk >= NB + NROWS) {                     // ---- M2 bf16 split prep
        int idx = (blk - (NB + NROWS)) * FTH + tid;   // idx = io*64 + r, 262144 total
        if (idx < 4096 * 64) {
            int r  = idx & 63;
            int io = idx >> 6;
            int i  = io >> 6;
            int o  = io & 63;
            float v = 0.0f;
            if (r < HDIM)      v = w3[r * 4096 + o * 64 + i];
            else if (r == 32)  v = b3[o * 64 + i];
            unsigned short h = f2bf(v);
            M2hi[idx] = h;
            M2lo[idx] = f2bf(v - bf2f(h));
        }
        return;
    }

    __shared__ float re[8704], im[8704];
    __shared__ float2 Tq[1025];
    build_table(Tq, tid);

    float* outF;
    long long orow;
    if (blk < NB) {                              // ---- basis row (inline MLP)
        int r = blk;
        for (int n = tid; n < 4096; n += FTH) {
            re[IDX(n + 4096)] = 0.0f;  im[IDX(n + 4096)] = 0.0f;
        }
        if (r < HDIM) {
            for (int t = tid; t < LSEQ; t += FTH) {
                float rel = -1.0f + 2.0f * (float)t / (float)(LSEQ - 1);
                float acc = b2[r];
                #pragma unroll 8
                for (int j = 0; j < HDIM; ++j)
                    acc = fmaf(sinf(OMEGA0 * fmaf(rel, w1[j], b1[j])), w2[j * HDIM + r], acc);
                float g = sinf(OMEGA0 * acc);
                int s = LSEQ - 1 - t;
                if (s & 1) im[IDX(s >> 1)] = g;
                else       re[IDX(s >> 1)] = g;
            }
        } else {
            for (int n = tid; n < 4096; n += FTH) {
                re[IDX(n)] = 1.0f;  im[IDX(n)] = 1.0f;
            }
        }
        outF = Hf;  orow = r;
    } else {                                     // ---- x row
        int row = blk - NB;
        const float2* zin = (const float2*)(x + (long long)row * LSEQ);
        for (int n = tid; n < 4096; n += FTH) {
            float2 v = zin[n];
            re[IDX(n)] = v.x;            im[IDX(n)] = v.y;
            re[IDX(n + 4096)] = 0.0f;    im[IDX(n + 4096)] = 0.0f;
        }
        outF = XYf;  orow = row;
    }

    fft8192_core8(re, im, Tq, tid);

    float2* out = (float2*)outF + orow * FSTRIDE;
    for (int k = tid; k <= 8192; k += FTH) {
        int k1 = IDX(BR(k & (N2 - 1)));
        int k2 = IDX(BR((N2 - k) & (N2 - 1)));
        float zr = re[k1], zi = im[k1];
        float wr = re[k2], wi = im[k2];
        float er = 0.5f * (zr + wr), ei = 0.5f * (zi - wi);
        float pr = 0.5f * (zi + wi), pi = 0.5f * (wr - zr);
        float s, c;
        __sincosf(-TWOPI * (float)k / 16384.0f, &s, &c);
        out[k] = make_float2(er + c * pr - s * pi,
                             ei + c * pi + s * pr);
    }
}

// ---------------------------------------------------------------- frequency-domain contraction (in-place on XYf)
// K-build on MFMA: per octant, wave w computes rows ii=w as a 16x16x(64) bf16
// matmul, 3-term split precision (Ahi*Bhi + Ahi*Blo + Alo*Bhi).
// A[R][r] = M2[r][i][o] from M2hi/lo[io][64r]; B[r][col] = Hblk 16 real cols.
// Einsum / staging / write-back: r7/r13 structure verbatim.
__global__ __launch_bounds__(512, 4) void contract_kernel(
    const float* __restrict__ Hf,
    const unsigned short* __restrict__ M2hi, const unsigned short* __restrict__ M2lo,
    float* __restrict__ XYf)
{
    __shared__ float Ks2[FBLK][1036];               // [f][(ii*64+o)*2+comp], stride 1036 (%32=12)
    __shared__ __align__(16) float2 Xq[8][8][FBLK]; // [b][ii][f]
    int tid = threadIdx.x;
    int o = tid & 63;
    int w = tid >> 6;                               // wave id 0..7
    int lane = tid & 63;
    int col = lane & 15;                            // B/C column = f-real col
    int krow0 = (lane >> 4) << 3;                   // k-block base 8*(lane>>4)
    long long f0 = (long long)blockIdx.x * FBLK;

    const float* Hblk = Hf + (size_t)blockIdx.x * (FBLK * 2);

    // ---- B fragments, once per block (bf16 hi/lo, r>=33 zero)
    bf16x8 Bhi[2], Blo[2];
    #pragma unroll
    for (int kb = 0; kb < 2; ++kb) {
        #pragma unroll
        for (int j = 0; j < 8; ++j) {
            int r = (kb << 5) + krow0 + j;
            float v = (r < NB) ? Hblk[(size_t)r * (FSTRIDE * 2) + col] : 0.0f;
            unsigned short h = f2bf(v);
            Bhi[kb][j] = (short)h;
            Blo[kb][j] = (short)f2bf(v - bf2f(h));
        }
    }

    float2 yacc[FBLK];
    #pragma unroll
    for (int f = 0; f < FBLK; ++f) yacc[f] = make_float2(0.f, 0.f);

    int sf  = tid & 7;
    int sii = (tid >> 3) & 7;
    int sb  = tid >> 6;
    int fcol = col >> 1, comp = col & 1;

    for (int oct = 0; oct < 8; ++oct) {
        __syncthreads();

        const float2* xsrc = (const float2*)XYf
            + (long long)((sb << 6) + (oct << 3) + sii) * FSTRIDE + f0 + sf;
        float2 xstage = *xsrc;

        // ---- K build (MFMA): wave w owns ii = w; 4 col-tiles of 16 o each
        int iobase = ((oct << 3) + w) << 6;          // global io base of this wave's i
        #pragma unroll
        for (int tt = 0; tt < 4; ++tt) {
            size_t abase = ((size_t)(iobase + (tt << 4) + col)) << 6;  // io*64 shorts
            bf16x8 Ah0 = *(const bf16x8*)(M2hi + abase + krow0);
            bf16x8 Ah1 = *(const bf16x8*)(M2hi + abase + 32 + krow0);
            bf16x8 Al0 = *(const bf16x8*)(M2lo + abase + krow0);
            bf16x8 Al1 = *(const bf16x8*)(M2lo + abase + 32 + krow0);
            f32x4 acc = {0.f, 0.f, 0.f, 0.f};
            acc = __builtin_amdgcn_mfma_f32_16x16x32_bf16(Ah0, Bhi[0], acc, 0, 0, 0);
            acc = __builtin_amdgcn_mfma_f32_16x16x32_bf16(Ah1, Bhi[1], acc, 0, 0, 0);
            acc = __builtin_amdgcn_mfma_f32_16x16x32_bf16(Ah0, Blo[0], acc, 0, 0, 0);
            acc = __builtin_amdgcn_mfma_f32_16x16x32_bf16(Ah1, Blo[1], acc, 0, 0, 0);
            acc = __builtin_amdgcn_mfma_f32_16x16x32_bf16(Al0, Bhi[0], acc, 0, 0, 0);
            acc = __builtin_amdgcn_mfma_f32_16x16x32_bf16(Al1, Bhi[1], acc, 0, 0, 0);
            #pragma unroll
            for (int p = 0; p < 4; ++p) {
                int oc = (tt << 4) + ((lane >> 4) << 2) + p;   // C row within 64
                Ks2[fcol][(((w << 6) + oc) << 1) + comp] = acc[p];
            }
        }
        Xq[sb][sii][sf] = xstage;
        __syncthreads();

        // ---- einsum: thread owns (o, b=w)
        #pragma unroll 2
        for (int ii = 0; ii < 8; ++ii) {
            const float4* xp = (const float4*)(&Xq[w][ii][0]);
            float4 x0 = xp[0], x1 = xp[1], x2 = xp[2], x3 = xp[3];
            float xr[FBLK] = {x0.x,x0.z,x1.x,x1.z,x2.x,x2.z,x3.x,x3.z};
            float xi[FBLK] = {x0.y,x0.w,x1.y,x1.w,x2.y,x2.w,x3.y,x3.w};
            #pragma unroll
            for (int f = 0; f < FBLK; ++f) {
                float2 kv = *(const float2*)(&Ks2[f][((ii << 6) + o) << 1]);
                yacc[f].x = fmaf(xr[f], kv.x, fmaf(-xi[f], kv.y, yacc[f].x));
                yacc[f].y = fmaf(xr[f], kv.y, fmaf( xi[f], kv.x, yacc[f].y));
            }
        }
    }
    __syncthreads();

    long long row = (long long)((w << 6) + o);
    float2* yp = (float2*)XYf + row * FSTRIDE + f0;
    #pragma unroll
    for (int f = 0; f < FBLK; ++f)
        if (f0 + f < NFREQ) yp[f] = yacc[f];
}

// ---------------------------------------------------------------- inverse rfft + bias
__global__ __launch_bounds__(FTH) void irfft_rows_kernel(
    const float* __restrict__ Yf, const float* __restrict__ bias,
    float* __restrict__ out)
{
    __shared__ float re[8704], im[8704];
    __shared__ float2 Tq[1025];
    int tid = threadIdx.x;
    int row = blockIdx.x;            // b*64 + o
    int o = row & 63;

    build_table(Tq, tid);

    const float2* G = (const float2*)Yf + (long long)row * FSTRIDE;
    for (int k = tid; k < N2; k += FTH) {
        float2 gk = G[k];
        float2 gm = G[8192 - k];
        float er = 0.5f * (gk.x + gm.x), ei = 0.5f * (gk.y - gm.y);
        float pr = 0.5f * (gk.x - gm.x), pi = 0.5f * (gk.y + gm.y);
        float s, c;
        __sincosf(TWOPI * (float)k / 16384.0f, &s, &c);
        float or_ = pr * c - pi * s;
        float oi_ = pr * s + pi * c;
        re[IDX(k)] = er - oi_;
        im[IDX(k)] = -(ei + or_);
    }
    fft8192_core8(re, im, Tq, tid);

    float bo = bias[o];
    const float scale = 1.0f / 8192.0f;
    float2* op = (float2*)(out + (long long)row * LSEQ);
    for (int n = tid; n < 4096; n += FTH) {
        int pn = IDX(BR(n));
        op[n] = make_float2(fmaf(re[pn], scale, bo), fmaf(-im[pn], scale, bo));
    }
}

// ---------------------------------------------------------------- launch
extern "C" void kernel_launch(void* const* d_in, const int* in_sizes, int n_in,
                              void* d_out, int out_size, void* d_ws, size_t ws_size,
                              hipStream_t stream)
{
    const float* x    = (const float*)d_in[0];
    const float* w1   = (const float*)d_in[1];
    const float* b1   = (const float*)d_in[2];
    const float* w2   = (const float*)d_in[3];
    const float* b2   = (const float*)d_in[4];
    const float* w3   = (const float*)d_in[5];
    const float* b3   = (const float*)d_in[6];
    const float* bias = (const float*)d_in[7];
    float* out = (float*)d_out;

    float* ws  = (float*)d_ws;
    float* Hf  = ws;                                       // NB*FSTRIDE*2 = 541728 floats
    unsigned short* M2hi = (unsigned short*)(Hf + NB * FSTRIDE * 2);   // 262144 shorts
    unsigned short* M2lo = M2hi + 4096 * 64;                           // 262144 shorts
    float* XYf = (float*)(M2lo + 4096 * 64);               // NROWS*FSTRIDE*2 floats

    int m2blocks = (4096 * 64 + FTH - 1) / FTH;            // 256
    fwd_kernel<<<dim3(NB + NROWS + m2blocks), dim3(FTH), 0, stream>>>(
        x, w1, b1, w2, b2, w3, b3, Hf, XYf, M2hi, M2lo);
    contract_kernel<<<dim3((NFREQ + FBLK - 1) / FBLK), dim3(512), 0, stream>>>(Hf, M2hi, M2lo, XYf);
    irfft_rows_kernel<<<dim3(NROWS), dim3(FTH), 0, stream>>>(XYf, bias, out);
}

// Round 20
// 224.097 us; speedup vs baseline: 1.2501x; 1.2501x over previous
//
#include <hip/hip_runtime.h>

// CKConv: y[b,o,n] = sum_i (x[b,i] * k[o,i])_causal[n] + bias[o]
// Rank-33 kernel: kr[o,i,t] = sum_r hbT[r][t] * M2[r][i][o]
// FFT path: Yf[b,o,f] = sum_i Xf[b,i,f]*Kf[o,i,f],  Kf = sum_r Hf[r,f]*M2[r,i,o]

#define LSEQ   8192
#define N2     8192      // half-size complex FFT length
#define HDIM   32
#define NB     33        // 32 SIREN basis rows + constant row (for b3)
#define NROWS  512       // B*Ci = 8*64
#define NFREQ  8193      // rfft bins of N=16384
#define FSTRIDE 8208     // complex row stride (16-aligned)
#define FBLK   8
#define FTH    1024      // FFT kernel block size
#define OMEGA0 30.0f
#define TWOPI  6.283185307179586f

// padded LDS index: caps bank conflicts at <=4-way across all FFT stages
#define IDX(i) ((i) + ((i) >> 4))
// 13-bit reversal (FFT core output order); consumers index through this
#define BR(k)  ((int)(__brev((unsigned)(k)) >> 19))

// ---------------------------------------------------------------- twiddle table
__device__ __forceinline__ void build_table(float2* Tq, int tid)
{
    for (int t = tid; t <= 1024; t += FTH) {
        float s, c;
        __sincosf(TWOPI * (float)t / 8192.0f, &s, &c);
        Tq[t] = make_float2(c, s);
    }
}

// ---------------------------------------------------------------- 8192-pt C2C FFT core
// 4 radix-8 DIF stages (outputs stored at slot brev3(p)) + final radix-2.
// Composite output order = 13-bit reversal; NO reversal pass — consumers use BR().
__device__ __forceinline__ void fft8192_core8(float* re, float* im,
                                              const float2* Tq, int tid)
{
    const float RC = 0.70710678118654752f;
    #pragma unroll
    for (int p = 10; p >= 1; p -= 3) {           // m = 1024,128,16,2
        int m = 1 << p;
        int tmul = 1 << (10 - p);
        __syncthreads();
        for (int u = tid; u < 1024; u += FTH) {
            int j = u & (m - 1);
            int base = ((u >> p) << (p + 3)) + j;
            float xr[8], xi[8];
            #pragma unroll
            for (int q = 0; q < 8; ++q) {
                int ix = IDX(base + q * m);
                xr[q] = re[ix]; xi[q] = im[ix];
            }
            float t0r=xr[0]+xr[4], t0i=xi[0]+xi[4];
            float t1r=xr[0]-xr[4], t1i=xi[0]-xi[4];
            float t2r=xr[2]+xr[6], t2i=xi[2]+xi[6];
            float t3r=xr[2]-xr[6], t3i=xi[2]-xi[6];
            float E0r=t0r+t2r, E0i=t0i+t2i;
            float E2r=t0r-t2r, E2i=t0i-t2i;
            float E1r=t1r+t3i, E1i=t1i-t3r;
            float E3r=t1r-t3i, E3i=t1i+t3r;
            float s0r=xr[1]+xr[5], s0i=xi[1]+xi[5];
            float s1r=xr[1]-xr[5], s1i=xi[1]-xi[5];
            float s2r=xr[3]+xr[7], s2i=xi[3]+xi[7];
            float s3r=xr[3]-xr[7], s3i=xi[3]-xi[7];
            float O0r=s0r+s2r, O0i=s0i+s2i;
            float O2r=s0r-s2r, O2i=s0i-s2i;
            float O1r=s1r+s3i, O1i=s1i-s3r;
            float O3r=s1r-s3i, O3i=s1i+s3r;
            float u1r=(O1r+O1i)*RC, u1i=(O1i-O1r)*RC;
            float u2r=O2i,          u2i=-O2r;
            float u3r=(O3i-O3r)*RC, u3i=-(O3r+O3i)*RC;
            float X0r=E0r+O0r, X0i=E0i+O0i;
            float X4r=E0r-O0r, X4i=E0i-O0i;
            float X1r=E1r+u1r, X1i=E1i+u1i;
            float X5r=E1r-u1r, X5i=E1i-u1i;
            float X2r=E2r+u2r, X2i=E2i+u2i;
            float X6r=E2r-u2r, X6i=E2i-u2i;
            float X3r=E3r+u3r, X3i=E3i+u3i;
            float X7r=E3r-u3r, X7i=E3i-u3i;
            float2 tq = Tq[j * tmul];
            float w1r = tq.x,               w1i = -tq.y;
            float w2r = w1r*w1r - w1i*w1i,  w2i = 2.f*w1r*w1i;
            float w3r = w2r*w1r - w2i*w1i,  w3i = w2r*w1i + w2i*w1r;
            float w4r = w2r*w2r - w2i*w2i,  w4i = 2.f*w2r*w2i;
            float w5r = w4r*w1r - w4i*w1i,  w5i = w4r*w1i + w4i*w1r;
            float w6r = w3r*w3r - w3i*w3i,  w6i = 2.f*w3r*w3i;
            float w7r = w4r*w3r - w4i*w3i,  w7i = w4r*w3i + w4i*w3r;
            int i0=IDX(base),       i1=IDX(base+m),   i2=IDX(base+2*m), i3=IDX(base+3*m);
            int i4=IDX(base+4*m),   i5=IDX(base+5*m), i6=IDX(base+6*m), i7=IDX(base+7*m);
            re[i0]=X0r;                     im[i0]=X0i;
            re[i1]=X4r*w4r - X4i*w4i;       im[i1]=X4r*w4i + X4i*w4r;
            re[i2]=X2r*w2r - X2i*w2i;       im[i2]=X2r*w2i + X2i*w2r;
            re[i3]=X6r*w6r - X6i*w6i;       im[i3]=X6r*w6i + X6i*w6r;
            re[i4]=X1r*w1r - X1i*w1i;       im[i4]=X1r*w1i + X1i*w1r;
            re[i5]=X5r*w5r - X5i*w5i;       im[i5]=X5r*w5i + X5i*w5r;
            re[i6]=X3r*w3r - X3i*w3i;       im[i6]=X3r*w3i + X3i*w3r;
            re[i7]=X7r*w7r - X7i*w7i;       im[i7]=X7r*w7i + X7i*w7r;
        }
    }
    __syncthreads();
    for (int u = tid; u < 4096; u += FTH) {
        int a = IDX(2 * u), b = IDX(2 * u + 1);
        float ar = re[a], ai = im[a];
        float br = re[b], bi = im[b];
        re[a] = ar + br; im[a] = ai + bi;
        re[b] = ar - br; im[b] = ai - bi;
    }
    __syncthreads();
}

// ---------------------------------------------------------------- merged forward kernel
__global__ __launch_bounds__(FTH) void fwd_kernel(
    const float* __restrict__ x,
    const float* __restrict__ w1, const float* __restrict__ b1,
    const float* __restrict__ w2, const float* __restrict__ b2,
    const float* __restrict__ w3, const float* __restrict__ b3,
    float* __restrict__ Hf, float* __restrict__ XYf, float* __restrict__ M2)
{
    int blk = blockIdx.x;
    int tid = threadIdx.x;

    if (blk >= NB + NROWS) {                     // ---- prep_m2 path (linear [r][i][o])
        int idx = (blk - (NB + NROWS)) * FTH + tid;
        if (idx < NB * 64 * 64) {
            int o = idx & 63;
            int i = (idx >> 6) & 63;
            int r = idx >> 12;
            M2[idx] = (r < HDIM) ? w3[r * 4096 + o * 64 + i] : b3[o * 64 + i];
        }
        return;
    }

    __shared__ float re[8704], im[8704];
    __shared__ float2 Tq[1025];
    build_table(Tq, tid);

    float* outF;
    long long orow;
    if (blk < NB) {                              // ---- basis row (inline MLP)
        int r = blk;
        for (int n = tid; n < 4096; n += FTH) {
            re[IDX(n + 4096)] = 0.0f;  im[IDX(n + 4096)] = 0.0f;
        }
        if (r < HDIM) {
            for (int t = tid; t < LSEQ; t += FTH) {
                float rel = -1.0f + 2.0f * (float)t / (float)(LSEQ - 1);
                float acc = b2[r];
                #pragma unroll 8
                for (int j = 0; j < HDIM; ++j)
                    acc = fmaf(sinf(OMEGA0 * fmaf(rel, w1[j], b1[j])), w2[j * HDIM + r], acc);
                float g = sinf(OMEGA0 * acc);
                int s = LSEQ - 1 - t;            // time-reversed position
                if (s & 1) im[IDX(s >> 1)] = g;
                else       re[IDX(s >> 1)] = g;
            }
        } else {                                 // constant row (b3)
            for (int n = tid; n < 4096; n += FTH) {
                re[IDX(n)] = 1.0f;  im[IDX(n)] = 1.0f;
            }
        }
        outF = Hf;  orow = r;
    } else {                                     // ---- x row
        int row = blk - NB;
        const float2* zin = (const float2*)(x + (long long)row * LSEQ);
        for (int n = tid; n < 4096; n += FTH) {
            float2 v = zin[n];
            re[IDX(n)] = v.x;            im[IDX(n)] = v.y;
            re[IDX(n + 4096)] = 0.0f;    im[IDX(n + 4096)] = 0.0f;
        }
        outF = XYf;  orow = row;
    }

    fft8192_core8(re, im, Tq, tid);

    // Hermitian fold (FFT output bit-reversed: read via BR())
    float2* out = (float2*)outF + orow * FSTRIDE;
    for (int k = tid; k <= 8192; k += FTH) {
        int k1 = IDX(BR(k & (N2 - 1)));
        int k2 = IDX(BR((N2 - k) & (N2 - 1)));
        float zr = re[k1], zi = im[k1];
        float wr = re[k2], wi = im[k2];
        float er = 0.5f * (zr + wr), ei = 0.5f * (zi - wi);
        float pr = 0.5f * (zi + wi), pi = 0.5f * (wr - zr);
        float s, c;
        __sincosf(-TWOPI * (float)k / 16384.0f, &s, &c);
        out[k] = make_float2(er + c * pr - s * pi,
                             ei + c * pi + s * pr);
    }
}

// ---------------------------------------------------------------- frequency-domain contraction (in-place on XYf)
// ROUND-7/13 VERSION VERBATIM (140 us): 512 threads = 8 waves, FBLK=8, 8 octants.
__global__ __launch_bounds__(512, 8) void contract_kernel(
    const float* __restrict__ Hf, const float* __restrict__ M2,
    float* __restrict__ XYf)
{
    __shared__ float2 Ks[FBLK][8][64];              // [f][ii][o]  32 KB
    __shared__ __align__(16) float2 Xq[8][8][FBLK]; // [b][ii][f]   4 KB
    int tid = threadIdx.x;
    int o = tid & 63;
    int w = tid >> 6;                               // wave id 0..7
    long long f0 = (long long)blockIdx.x * FBLK;

    const float* Hblk = Hf + (size_t)blockIdx.x * (FBLK * 2);   // uniform base

    float2 yacc[FBLK];
    #pragma unroll
    for (int f = 0; f < FBLK; ++f) yacc[f] = make_float2(0.f, 0.f);

    // X staging coords: thread stages one float2 Xq[sb][sii][sf]
    int sf  = tid & 7;
    int sii = (tid >> 3) & 7;
    int sb  = tid >> 6;

    for (int oct = 0; oct < 8; ++oct) {
        __syncthreads();   // prev einsum complete before Ks/Xq overwrite

        // issue X stage load early; committed to LDS after K-build
        const float2* xsrc = (const float2*)XYf
            + (long long)((sb << 6) + (oct << 3) + sii) * FSTRIDE + f0 + sf;
        float2 xstage = *xsrc;

        // ---- K build: i = oct*8 + w
        float2 kacc[FBLK];
        #pragma unroll
        for (int f = 0; f < FBLK; ++f) kacc[f] = make_float2(0.f, 0.f);

        const float* mp = M2 + (((oct << 3) + w) << 6) + o;
        #pragma unroll 3
        for (int r = 0; r < NB; ++r) {
            // block-uniform H row -> scalar loads (SGPRs)
            const float4* hp = (const float4*)(Hblk + (size_t)r * (size_t)(FSTRIDE * 2));
            float4 h0 = hp[0], h1 = hp[1], h2 = hp[2], h3 = hp[3];
            float m0 = mp[r << 12];
            float hr_[FBLK] = {h0.x,h0.z,h1.x,h1.z,h2.x,h2.z,h3.x,h3.z};
            float hi_[FBLK] = {h0.y,h0.w,h1.y,h1.w,h2.y,h2.w,h3.y,h3.w};
            #pragma unroll
            for (int f = 0; f < FBLK; ++f) {
                kacc[f].x = fmaf(m0, hr_[f], kacc[f].x);
                kacc[f].y = fmaf(m0, hi_[f], kacc[f].y);
            }
        }
        // commit staged X and built K to LDS
        Xq[sb][sii][sf] = xstage;
        #pragma unroll
        for (int f = 0; f < FBLK; ++f)
            Ks[f][w][o] = kacc[f];
        __syncthreads();

        // ---- einsum: thread owns (o, b=w)
        #pragma unroll 2
        for (int ii = 0; ii < 8; ++ii) {
            const float4* xp = (const float4*)(&Xq[w][ii][0]);
            float4 x0 = xp[0], x1 = xp[1], x2 = xp[2], x3 = xp[3];
            float xr[FBLK] = {x0.x,x0.z,x1.x,x1.z,x2.x,x2.z,x3.x,x3.z};
            float xi[FBLK] = {x0.y,x0.w,x1.y,x1.w,x2.y,x2.w,x3.y,x3.w};
            #pragma unroll
            for (int f = 0; f < FBLK; ++f) {
                float2 kv = Ks[f][ii][o];
                yacc[f].x = fmaf(xr[f], kv.x, fmaf(-xi[f], kv.y, yacc[f].x));
                yacc[f].y = fmaf(xr[f], kv.y, fmaf( xi[f], kv.x, yacc[f].y));
            }
        }
    }
    __syncthreads();   // all staging reads done before in-place write-back

    long long row = (long long)((w << 6) + o);
    float2* yp = (float2*)XYf + row * FSTRIDE + f0;
    #pragma unroll
    for (int f = 0; f < FBLK; ++f)
        if (f0 + f < NFREQ) yp[f] = yacc[f];
}

// ---------------------------------------------------------------- inverse rfft + bias, keep first 8192 samples
__global__ __launch_bounds__(FTH) void irfft_rows_kernel(
    const float* __restrict__ Yf, const float* __restrict__ bias,
    float* __restrict__ out)
{
    __shared__ float re[8704], im[8704];
    __shared__ float2 Tq[1025];
    int tid = threadIdx.x;
    int row = blockIdx.x;            // b*64 + o
    int o = row & 63;

    build_table(Tq, tid);

    const float2* G = (const float2*)Yf + (long long)row * FSTRIDE;
    for (int k = tid; k < N2; k += FTH) {
        float2 gk = G[k];
        float2 gm = G[8192 - k];
        float er = 0.5f * (gk.x + gm.x), ei = 0.5f * (gk.y - gm.y);
        float pr = 0.5f * (gk.x - gm.x), pi = 0.5f * (gk.y + gm.y);
        float s, c;
        __sincosf(TWOPI * (float)k / 16384.0f, &s, &c);
        float or_ = pr * c - pi * s;
        float oi_ = pr * s + pi * c;
        re[IDX(k)] = er - oi_;            // Re(Z)
        im[IDX(k)] = -(ei + or_);         // -Im(Z)  (conjugate)
    }
    fft8192_core8(re, im, Tq, tid);

    float bo = bias[o];
    const float scale = 1.0f / 8192.0f;
    float2* op = (float2*)(out + (long long)row * LSEQ);
    for (int n = tid; n < 4096; n += FTH) {
        int pn = IDX(BR(n));
        op[n] = make_float2(fmaf(re[pn], scale, bo), fmaf(-im[pn], scale, bo));
    }
}

// ---------------------------------------------------------------- launch
extern "C" void kernel_launch(void* const* d_in, const int* in_sizes, int n_in,
                              void* d_out, int out_size, void* d_ws, size_t ws_size,
                              hipStream_t stream)
{
    const float* x    = (const float*)d_in[0];
    const float* w1   = (const float*)d_in[1];
    const float* b1   = (const float*)d_in[2];
    const float* w2   = (const float*)d_in[3];
    const float* b2   = (const float*)d_in[4];
    const float* w3   = (const float*)d_in[5];
    const float* b3   = (const float*)d_in[6];
    const float* bias = (const float*)d_in[7];
    float* out = (float*)d_out;

    float* ws  = (float*)d_ws;
    float* Hf  = ws;                               // NB*FSTRIDE*2     = 541728
    float* M2  = Hf + NB * FSTRIDE * 2;            // NB*64*64         = 135168
    float* XYf = M2 + NB * 64 * 64;                // NROWS*FSTRIDE*2  = 8404992

    int m2blocks = (NB * 64 * 64 + FTH - 1) / FTH;
    fwd_kernel<<<dim3(NB + NROWS + m2blocks), dim3(FTH), 0, stream>>>(
        x, w1, b1, w2, b2, w3, b3, Hf, XYf, M2);
    contract_kernel<<<dim3((NFREQ + FBLK - 1) / FBLK), dim3(512), 0, stream>>>(Hf, M2, XYf);
    irfft_rows_kernel<<<dim3(NROWS), dim3(FTH), 0, stream>>>(XYf, bias, out);
}